// Round 10
// baseline (152.667 us; speedup 1.0000x reference)
//
#include <hip/hip_runtime.h>
#include <hip/hip_bf16.h>
#include <type_traits>
#include <math.h>

typedef __bf16 bf16x8 __attribute__((ext_vector_type(8)));
typedef float floatx4 __attribute__((ext_vector_type(4)));
typedef float floatx16 __attribute__((ext_vector_type(16)));

#define S_LEN 2048
#define D_DIM 128
#define NTOK (2 * 16 * 2048)  // B*H*S = 65536 rows
#define KVB 64
#define NKV (S_LEN / KVB)     // 32 kv tiles

// ---------------------------------------------------------------------------
// proj body: stages W once, then processes 4 chunks of 64 rows.
// ---------------------------------------------------------------------------
template <typename TIN, typename TOUT>
__device__ __forceinline__ void proj_body4(
    const TIN* __restrict__ x, const float* __restrict__ W,
    const float* __restrict__ b, TOUT* __restrict__ y, float out_scale,
    int chunk0, __bf16 (*Wl)[128]) {
  const int tid = threadIdx.x;
  const int wave = tid >> 6, lane = tid & 63;
  const int g = lane >> 4, lr = lane & 15;

  for (int it = 0; it < 16; ++it) {
    int lin = it * 1024 + tid * 4;
    float4 w4 = *reinterpret_cast<const float4*>(W + lin);
    int r = lin >> 7, c = lin & 127;
    Wl[r][c]     = (__bf16)w4.x;
    Wl[r][c + 1] = (__bf16)w4.y;
    Wl[r][c + 2] = (__bf16)w4.z;
    Wl[r][c + 3] = (__bf16)w4.w;
  }
  __syncthreads();

  float be[8];
#pragma unroll
  for (int nt = 0; nt < 8; ++nt) be[nt] = b[nt * 16 + lr];

  for (int ch = 0; ch < 4; ++ch) {
    const int rbase = (chunk0 + ch) * 64;
    const int arow = rbase + wave * 16 + lr;

    floatx4 acc[8];
#pragma unroll
    for (int i = 0; i < 8; ++i) acc[i] = floatx4{0.f, 0.f, 0.f, 0.f};

#pragma unroll
    for (int kc = 0; kc < 4; ++kc) {
      bf16x8 af;
      const TIN* xp = x + (size_t)arow * D_DIM + kc * 32 + g * 8;
      if constexpr (std::is_same<TIN, float>::value) {
        float4 f0 = *reinterpret_cast<const float4*>(xp);
        float4 f1 = *reinterpret_cast<const float4*>(xp + 4);
        af[0] = (__bf16)f0.x; af[1] = (__bf16)f0.y;
        af[2] = (__bf16)f0.z; af[3] = (__bf16)f0.w;
        af[4] = (__bf16)f1.x; af[5] = (__bf16)f1.y;
        af[6] = (__bf16)f1.z; af[7] = (__bf16)f1.w;
      } else {
        af = *reinterpret_cast<const bf16x8*>(xp);
      }
#pragma unroll
      for (int nt = 0; nt < 8; ++nt) {
        bf16x8 wf = *reinterpret_cast<const bf16x8*>(&Wl[nt * 16 + lr][kc * 32 + g * 8]);
        acc[nt] = __builtin_amdgcn_mfma_f32_16x16x32_bf16(af, wf, acc[nt], 0, 0, 0);
      }
    }

#pragma unroll
    for (int nt = 0; nt < 8; ++nt) {
      int e = nt * 16 + lr;
#pragma unroll
      for (int j = 0; j < 4; ++j) {
        int row = rbase + wave * 16 + g * 4 + j;
        float val = (acc[nt][j] + be[nt]) * out_scale;
        y[(size_t)row * D_DIM + e] = (TOUT)val;
      }
    }
  }
}

__global__ __launch_bounds__(256) void qkv_proj_kernel(
    const float* __restrict__ xq, const float* __restrict__ xk,
    const float* __restrict__ xv, const float* __restrict__ Wq,
    const float* __restrict__ Wk, const float* __restrict__ Wv,
    const float* __restrict__ bq, const float* __restrict__ bk,
    const float* __restrict__ bv, __bf16* yq, __bf16* yk, __bf16* yv,
    float qscale) {
  __shared__ alignas(16) __bf16 Wl[128][128];
  const int which = blockIdx.y;
  const float* x = which == 0 ? xq : which == 1 ? xk : xv;
  const float* W = which == 0 ? Wq : which == 1 ? Wk : Wv;
  const float* b = which == 0 ? bq : which == 1 ? bk : bv;
  __bf16* y = which == 0 ? yq : which == 1 ? yk : yv;
  float sc = which == 0 ? qscale : 1.0f;
  proj_body4<float, __bf16>(x, W, b, y, sc, blockIdx.x * 4, Wl);
}

__global__ __launch_bounds__(256) void o_proj_kernel(
    const __bf16* __restrict__ x, const float* __restrict__ W,
    const float* __restrict__ b, float* __restrict__ y) {
  __shared__ alignas(16) __bf16 Wl[128][128];
  proj_body4<__bf16, float>(x, W, b, y, 1.0f, blockIdx.x * 4, Wl);
}

// ---------------------------------------------------------------------------
__device__ __forceinline__ unsigned swz(int row, unsigned byteoff) {
  return byteoff ^ (((unsigned)(row ^ (row >> 3)) & 7u) << 4);
}

__device__ __forceinline__ unsigned pack2(float lo, float hi) {
  union { __bf16 h[2]; unsigned u; } r;
  r.h[0] = (__bf16)lo; r.h[1] = (__bf16)hi;
  return r.u;
}

// ---------------------------------------------------------------------------
// attn_kernel v10: skewed pipeline. Body t (2 barriers, both cheap):
//   barA; write K(t+1)->bufK[(t+1)&1], V(t)->bufV[t&1] (regs from body t-1);
//   barB; prefetch-issue K(t+2), V(t+1);
//   QK(t+1) -> st_next   [independent of softmax(t) chain -> intra-wave
//   softmax(st_cur)       MFMA/DS overlaps VALU]
//   PV(t) -> ot; st_cur = st_next.
// Race proof: each buffer's write is >=2 barriers after its last reader
// (bufK[(t+1)&1] last read by QK(t-1) in body t-2; bufV[t&1] by PV(t-2)).
// barA vmcnt-drain only sees loads issued a full body earlier (aged);
// barB drains only the just-issued ds_writes.
// K region: smem[0..32768) two 16 KB bufs; V: smem[32768..65536).
// ---------------------------------------------------------------------------
__global__ __launch_bounds__(256, 2) void attn_kernel(
    const __bf16* __restrict__ q, const __bf16* __restrict__ k,
    const __bf16* __restrict__ v, __bf16* __restrict__ o) {
  __shared__ alignas(16) unsigned char smem[65536];

  const int tid = threadIdx.x;
  const int wave = tid >> 6, lane = tid & 63;
  const int ql = lane & 31;
  const int h = lane >> 5;

  const int bh = blockIdx.x;
  const int qbase = blockIdx.y * 128;
  const __bf16* qp = q + (size_t)bh * S_LEN * D_DIM;
  const __bf16* kp = k + (size_t)bh * S_LEN * D_DIM;
  const __bf16* vp = v + (size_t)bh * S_LEN * D_DIM;
  __bf16* op = o + (size_t)bh * S_LEN * D_DIM;

  const int qrow = qbase + wave * 32 + ql;
  bf16x8 qf[8];
#pragma unroll
  for (int kc = 0; kc < 8; ++kc)
    qf[kc] = *reinterpret_cast<const bf16x8*>(
        qp + (size_t)qrow * D_DIM + kc * 16 + h * 8);

  floatx16 ot[4];
#pragma unroll
  for (int d = 0; d < 4; ++d)
#pragma unroll
    for (int r = 0; r < 16; ++r) ot[d][r] = 0.f;
  float m_r = -1e30f, l_r = 0.f;

  const int pr = (tid >> 4) * 2;
  const int ce = (tid & 15) * 8;

  // ---- precomputed LDS byte-offsets (loop-invariant) ----
  unsigned ka[16];
#pragma unroll
  for (int kvh = 0; kvh < 2; ++kvh)
#pragma unroll
    for (int kc = 0; kc < 8; ++kc) {
      int row = kvh * 32 + ql;
      ka[kvh * 8 + kc] = swz(row, row * 256u + kc * 32u + h * 16u);
    }
  unsigned va[16];
#pragma unroll
  for (int ks = 0; ks < 4; ++ks)
#pragma unroll
    for (int db = 0; db < 4; ++db) {
      int row = db * 32 + ql;
      va[ks * 4 + db] = 32768u + swz(row, row * 128u + ks * 32u + h * 16u);
    }
  unsigned kw[4];
  {
    int rows[4] = {pr, pr + 1, pr + 32, pr + 33};
#pragma unroll
    for (int i = 0; i < 4; ++i)
      kw[i] = swz(rows[i], rows[i] * 256u + ce * 2u);
  }
  unsigned vw[16];
#pragma unroll
  for (int e = 0; e < 8; ++e) {
    int d = ce + e;
    vw[e * 2]     = 32768u + swz(d, d * 128u + pr * 2u);
    vw[e * 2 + 1] = 32768u + swz(d, d * 128u + (pr + 32) * 2u);
  }

  // persistent staged regs (loaded body t, written body t+1 top)
  bf16x8 kS0, kS1, kS2, kS3;
  union { bf16x8 v8; unsigned short s[8]; } vS0, vS1, vS2, vS3;

  // ---- prologue: direct-stage K(0)->bufK0; preload K(1),V(0); QK(0) ----
  {
    const __bf16* kr = kp + (size_t)pr * D_DIM + ce;
    bf16x8 a0 = *reinterpret_cast<const bf16x8*>(kr);
    bf16x8 a1 = *reinterpret_cast<const bf16x8*>(kr + D_DIM);
    bf16x8 a2 = *reinterpret_cast<const bf16x8*>(kr + 32 * D_DIM);
    bf16x8 a3 = *reinterpret_cast<const bf16x8*>(kr + 33 * D_DIM);
    *reinterpret_cast<bf16x8*>(smem + kw[0]) = a0;
    *reinterpret_cast<bf16x8*>(smem + kw[1]) = a1;
    *reinterpret_cast<bf16x8*>(smem + kw[2]) = a2;
    *reinterpret_cast<bf16x8*>(smem + kw[3]) = a3;
    const __bf16* k1 = kp + ((size_t)KVB + pr) * D_DIM + ce;
    kS0 = *reinterpret_cast<const bf16x8*>(k1);
    kS1 = *reinterpret_cast<const bf16x8*>(k1 + D_DIM);
    kS2 = *reinterpret_cast<const bf16x8*>(k1 + 32 * D_DIM);
    kS3 = *reinterpret_cast<const bf16x8*>(k1 + 33 * D_DIM);
    const __bf16* v0 = vp + (size_t)pr * D_DIM + ce;
    vS0.v8 = *reinterpret_cast<const bf16x8*>(v0);
    vS1.v8 = *reinterpret_cast<const bf16x8*>(v0 + D_DIM);
    vS2.v8 = *reinterpret_cast<const bf16x8*>(v0 + 32 * D_DIM);
    vS3.v8 = *reinterpret_cast<const bf16x8*>(v0 + 33 * D_DIM);
  }
  __syncthreads();

  floatx16 stc0, stc1, stn0, stn1;
#pragma unroll
  for (int r = 0; r < 16; ++r) { stc0[r] = 0.f; stc1[r] = 0.f; }
  __builtin_amdgcn_s_setprio(1);
#pragma unroll
  for (int kc = 0; kc < 8; ++kc) {
    bf16x8 kf0 = *reinterpret_cast<const bf16x8*>(smem + ka[kc]);
    bf16x8 kf1 = *reinterpret_cast<const bf16x8*>(smem + ka[8 + kc]);
    stc0 = __builtin_amdgcn_mfma_f32_32x32x16_bf16(kf0, qf[kc], stc0, 0, 0, 0);
    stc1 = __builtin_amdgcn_mfma_f32_32x32x16_bf16(kf1, qf[kc], stc1, 0, 0, 0);
  }
  __builtin_amdgcn_s_setprio(0);

  // running prefetch pointers: K(t+2) and V(t+1) as seen from body t
  const __bf16* krp = kp + ((size_t)(2 * KVB) + pr) * D_DIM + ce;
  const __bf16* vrp = vp + ((size_t)KVB + pr) * D_DIM + ce;

#pragma unroll 2
  for (int t = 0; t < NKV; ++t) {
    const unsigned pK = (unsigned)((t + 1) & 1) * 16384u;
    const unsigned pV = (unsigned)(t & 1) * 16384u;
    const bool hasN = (t + 1 < NKV);
    const bool hasK2 = (t + 2 < NKV);

    __syncthreads();  // barrier A
    if (hasN) {  // write K(t+1)
      *reinterpret_cast<bf16x8*>(smem + pK + kw[0]) = kS0;
      *reinterpret_cast<bf16x8*>(smem + pK + kw[1]) = kS1;
      *reinterpret_cast<bf16x8*>(smem + pK + kw[2]) = kS2;
      *reinterpret_cast<bf16x8*>(smem + pK + kw[3]) = kS3;
    }
    {  // write V(t)
#pragma unroll
      for (int e = 0; e < 8; ++e) {
        unsigned w0 = (unsigned)vS0.s[e] | ((unsigned)vS1.s[e] << 16);
        unsigned w1 = (unsigned)vS2.s[e] | ((unsigned)vS3.s[e] << 16);
        *reinterpret_cast<unsigned*>(smem + pV + vw[e * 2]) = w0;
        *reinterpret_cast<unsigned*>(smem + pV + vw[e * 2 + 1]) = w1;
      }
    }
    __syncthreads();  // barrier B (drains only the ds_writes above)

    if (hasK2) {  // prefetch K(t+2)
      kS0 = *reinterpret_cast<const bf16x8*>(krp);
      kS1 = *reinterpret_cast<const bf16x8*>(krp + D_DIM);
      kS2 = *reinterpret_cast<const bf16x8*>(krp + 32 * D_DIM);
      kS3 = *reinterpret_cast<const bf16x8*>(krp + 33 * D_DIM);
      krp += (size_t)KVB * D_DIM;
    }
    if (hasN) {  // prefetch V(t+1)
      vS0.v8 = *reinterpret_cast<const bf16x8*>(vrp);
      vS1.v8 = *reinterpret_cast<const bf16x8*>(vrp + D_DIM);
      vS2.v8 = *reinterpret_cast<const bf16x8*>(vrp + 32 * D_DIM);
      vS3.v8 = *reinterpret_cast<const bf16x8*>(vrp + 33 * D_DIM);
      vrp += (size_t)KVB * D_DIM;
    }

    // ---- QK(t+1) -> st_next (independent of softmax(t) chain) ----
    if (hasN) {
#pragma unroll
      for (int r = 0; r < 16; ++r) { stn0[r] = 0.f; stn1[r] = 0.f; }
      __builtin_amdgcn_s_setprio(1);
#pragma unroll
      for (int kc = 0; kc < 8; ++kc) {
        bf16x8 kf0 = *reinterpret_cast<const bf16x8*>(smem + pK + ka[kc]);
        bf16x8 kf1 = *reinterpret_cast<const bf16x8*>(smem + pK + ka[8 + kc]);
        stn0 = __builtin_amdgcn_mfma_f32_32x32x16_bf16(kf0, qf[kc], stn0, 0, 0, 0);
        stn1 = __builtin_amdgcn_mfma_f32_32x32x16_bf16(kf1, qf[kc], stn1, 0, 0, 0);
      }
      __builtin_amdgcn_s_setprio(0);
    }

    // ---- softmax(t) on st_cur (exp2 domain, max3-shaped tree, T13) ----
    float m16[16];
#pragma unroll
    for (int i = 0; i < 16; ++i) m16[i] = fmaxf(stc0[i], stc1[i]);
    float a0 = fmaxf(fmaxf(m16[0], m16[1]), m16[2]);
    float a1 = fmaxf(fmaxf(m16[3], m16[4]), m16[5]);
    float a2 = fmaxf(fmaxf(m16[6], m16[7]), m16[8]);
    float a3 = fmaxf(fmaxf(m16[9], m16[10]), m16[11]);
    float a4 = fmaxf(fmaxf(m16[12], m16[13]), m16[14]);
    float pmax = fmaxf(fmaxf(fmaxf(a0, a1), a2),
                       fmaxf(fmaxf(a3, a4), m16[15]));
    pmax = fmaxf(pmax, __shfl_xor(pmax, 32));
    if (!__all(pmax - m_r <= 8.0f)) {
      float mnew = fmaxf(m_r, pmax);
      float sc_f = __builtin_amdgcn_exp2f(m_r - mnew);
      m_r = mnew;
      l_r *= sc_f;
#pragma unroll
      for (int d = 0; d < 4; ++d)
#pragma unroll
        for (int r = 0; r < 16; ++r) ot[d][r] *= sc_f;
    }
#pragma unroll
    for (int r = 0; r < 16; ++r) {
      stc0[r] = __builtin_amdgcn_exp2f(stc0[r] - m_r);
      stc1[r] = __builtin_amdgcn_exp2f(stc1[r] - m_r);
    }
    float s8[8];
#pragma unroll
    for (int i = 0; i < 8; ++i)
      s8[i] = (stc0[i] + stc0[i + 8]) + (stc1[i] + stc1[i + 8]);
    float psum = ((s8[0] + s8[4]) + (s8[1] + s8[5])) +
                 ((s8[2] + s8[6]) + (s8[3] + s8[7]));
    psum += __shfl_xor(psum, 32);
    l_r += psum;

    // ---- P^T fragments + PV(t) ----
#pragma unroll
    for (int ks = 0; ks < 4; ++ks) {
      const int r2a = (2 * ks) & 3;
      const int r2b = r2a + 1;
      float p0, p1, p2, p3, p4, p5, p6, p7;
      if (ks < 2) {
        p0 = stc0[r2a * 4 + 0]; p1 = stc0[r2a * 4 + 1];
        p2 = stc0[r2a * 4 + 2]; p3 = stc0[r2a * 4 + 3];
        p4 = stc0[r2b * 4 + 0]; p5 = stc0[r2b * 4 + 1];
        p6 = stc0[r2b * 4 + 2]; p7 = stc0[r2b * 4 + 3];
      } else {
        p0 = stc1[r2a * 4 + 0]; p1 = stc1[r2a * 4 + 1];
        p2 = stc1[r2a * 4 + 2]; p3 = stc1[r2a * 4 + 3];
        p4 = stc1[r2b * 4 + 0]; p5 = stc1[r2b * 4 + 1];
        p6 = stc1[r2b * 4 + 2]; p7 = stc1[r2b * 4 + 3];
      }
      unsigned ua0 = pack2(p0, p1);
      unsigned ua1 = pack2(p2, p3);
      unsigned ub0 = pack2(p4, p5);
      unsigned ub1 = pack2(p6, p7);
      union { unsigned u[4]; bf16x8 v8; } pw;
#if __has_builtin(__builtin_amdgcn_permlane32_swap)
      {
        auto r0 = __builtin_amdgcn_permlane32_swap(ua0, ub0, false, false);
        auto r1 = __builtin_amdgcn_permlane32_swap(ua1, ub1, false, false);
        pw.u[0] = r0[0];
        pw.u[1] = r1[0];
        pw.u[2] = r0[1];
        pw.u[3] = r1[1];
      }
#else
      {
        unsigned a0x = __shfl_xor(ua0, 32), a1x = __shfl_xor(ua1, 32);
        unsigned b0x = __shfl_xor(ub0, 32), b1x = __shfl_xor(ub1, 32);
        pw.u[0] = h ? b0x : ua0;
        pw.u[1] = h ? b1x : ua1;
        pw.u[2] = h ? ub0 : a0x;
        pw.u[3] = h ? ub1 : a1x;
      }
#endif
      __builtin_amdgcn_s_setprio(1);
#pragma unroll
      for (int db = 0; db < 4; ++db) {
        bf16x8 vf = *reinterpret_cast<const bf16x8*>(smem + pV + va[ks * 4 + db]);
        ot[db] = __builtin_amdgcn_mfma_f32_32x32x16_bf16(vf, pw.v8, ot[db], 0, 0, 0);
      }
      __builtin_amdgcn_s_setprio(0);
    }

    // ---- shift pipeline ----
    if (hasN) { stc0 = stn0; stc1 = stn1; }
  }

  // ---- epilogue: O^T -> LDS transpose -> coalesced stores ----
  __syncthreads();
  const float inv_l = 1.0f / l_r;
  const int qloc = wave * 32 + ql;
#pragma unroll
  for (int db = 0; db < 4; ++db)
#pragma unroll
    for (int r = 0; r < 16; ++r) {
      int d = db * 32 + (r & 3) + 8 * (r >> 2) + 4 * h;
      *reinterpret_cast<__bf16*>(smem + swz(qloc, qloc * 256u + d * 2u)) =
          (__bf16)(ot[db][r] * inv_l);
    }
  __syncthreads();
#pragma unroll
  for (int it = 0; it < 8; ++it) {
    int r = tid >> 1;
    int c = (tid & 1) * 64 + it * 8;
    bf16x8 val = *reinterpret_cast<const bf16x8*>(smem + swz(r, r * 256u + c * 2u));
    *reinterpret_cast<bf16x8*>(op + (size_t)(qbase + r) * D_DIM + c) = val;
  }
}

// ---------------------------------------------------------------------------
extern "C" void kernel_launch(void* const* d_in, const int* in_sizes, int n_in,
                              void* d_out, int out_size, void* d_ws, size_t ws_size,
                              hipStream_t stream) {
  const float* query = (const float*)d_in[0];
  const float* key_  = (const float*)d_in[1];
  const float* value = (const float*)d_in[2];
  const float* Wq = (const float*)d_in[3];
  const float* bq = (const float*)d_in[4];
  const float* Wk = (const float*)d_in[5];
  const float* bk = (const float*)d_in[6];
  const float* Wv = (const float*)d_in[7];
  const float* bv = (const float*)d_in[8];
  const float* Wo = (const float*)d_in[9];
  const float* bo = (const float*)d_in[10];

  __bf16* vws = (__bf16*)d_ws;
  __bf16* aws = vws + (size_t)NTOK * D_DIM;
  __bf16* qws = (__bf16*)d_out;
  __bf16* kws = qws + (size_t)NTOK * D_DIM;

  // q scale = log2(e)/sqrt(128): softmax runs in exp2 domain
  const float qscale = 0.1275174490036f;

  qkv_proj_kernel<<<dim3(NTOK / 256, 3), dim3(256), 0, stream>>>(
      query, key_, value, Wq, Wk, Wv, bq, bk, bv, qws, kws, vws, qscale);

  attn_kernel<<<dim3(32, 16), dim3(256), 0, stream>>>(qws, kws, vws, aws);

  o_proj_kernel<<<NTOK / 256, dim3(256), 0, stream>>>(aws, Wo, bo, (float*)d_out);
}

// Round 11
// 132.342 us; speedup vs baseline: 1.1536x; 1.1536x over previous
//
#include <hip/hip_runtime.h>
#include <hip/hip_bf16.h>
#include <type_traits>
#include <math.h>

typedef __bf16 bf16x8 __attribute__((ext_vector_type(8)));
typedef float floatx4 __attribute__((ext_vector_type(4)));
typedef float floatx16 __attribute__((ext_vector_type(16)));

#define S_LEN 2048
#define D_DIM 128
#define NTOK (2 * 16 * 2048)  // B*H*S = 65536 rows
#define KVB 64
#define NKV (S_LEN / KVB)     // 32 kv tiles

// ---------------------------------------------------------------------------
// proj body: stages W once, then processes 4 chunks of 64 rows.
// ---------------------------------------------------------------------------
template <typename TIN, typename TOUT>
__device__ __forceinline__ void proj_body4(
    const TIN* __restrict__ x, const float* __restrict__ W,
    const float* __restrict__ b, TOUT* __restrict__ y, float out_scale,
    int chunk0, __bf16 (*Wl)[128]) {
  const int tid = threadIdx.x;
  const int wave = tid >> 6, lane = tid & 63;
  const int g = lane >> 4, lr = lane & 15;

  for (int it = 0; it < 16; ++it) {
    int lin = it * 1024 + tid * 4;
    float4 w4 = *reinterpret_cast<const float4*>(W + lin);
    int r = lin >> 7, c = lin & 127;
    Wl[r][c]     = (__bf16)w4.x;
    Wl[r][c + 1] = (__bf16)w4.y;
    Wl[r][c + 2] = (__bf16)w4.z;
    Wl[r][c + 3] = (__bf16)w4.w;
  }
  __syncthreads();

  float be[8];
#pragma unroll
  for (int nt = 0; nt < 8; ++nt) be[nt] = b[nt * 16 + lr];

  for (int ch = 0; ch < 4; ++ch) {
    const int rbase = (chunk0 + ch) * 64;
    const int arow = rbase + wave * 16 + lr;

    floatx4 acc[8];
#pragma unroll
    for (int i = 0; i < 8; ++i) acc[i] = floatx4{0.f, 0.f, 0.f, 0.f};

#pragma unroll
    for (int kc = 0; kc < 4; ++kc) {
      bf16x8 af;
      const TIN* xp = x + (size_t)arow * D_DIM + kc * 32 + g * 8;
      if constexpr (std::is_same<TIN, float>::value) {
        float4 f0 = *reinterpret_cast<const float4*>(xp);
        float4 f1 = *reinterpret_cast<const float4*>(xp + 4);
        af[0] = (__bf16)f0.x; af[1] = (__bf16)f0.y;
        af[2] = (__bf16)f0.z; af[3] = (__bf16)f0.w;
        af[4] = (__bf16)f1.x; af[5] = (__bf16)f1.y;
        af[6] = (__bf16)f1.z; af[7] = (__bf16)f1.w;
      } else {
        af = *reinterpret_cast<const bf16x8*>(xp);
      }
#pragma unroll
      for (int nt = 0; nt < 8; ++nt) {
        bf16x8 wf = *reinterpret_cast<const bf16x8*>(&Wl[nt * 16 + lr][kc * 32 + g * 8]);
        acc[nt] = __builtin_amdgcn_mfma_f32_16x16x32_bf16(af, wf, acc[nt], 0, 0, 0);
      }
    }

#pragma unroll
    for (int nt = 0; nt < 8; ++nt) {
      int e = nt * 16 + lr;
#pragma unroll
      for (int j = 0; j < 4; ++j) {
        int row = rbase + wave * 16 + g * 4 + j;
        float val = (acc[nt][j] + be[nt]) * out_scale;
        y[(size_t)row * D_DIM + e] = (TOUT)val;
      }
    }
  }
}

__global__ __launch_bounds__(256) void qkv_proj_kernel(
    const float* __restrict__ xq, const float* __restrict__ xk,
    const float* __restrict__ xv, const float* __restrict__ Wq,
    const float* __restrict__ Wk, const float* __restrict__ Wv,
    const float* __restrict__ bq, const float* __restrict__ bk,
    const float* __restrict__ bv, __bf16* yq, __bf16* yk, __bf16* yv,
    float qscale) {
  __shared__ alignas(16) __bf16 Wl[128][128];
  const int which = blockIdx.y;
  const float* x = which == 0 ? xq : which == 1 ? xk : xv;
  const float* W = which == 0 ? Wq : which == 1 ? Wk : Wv;
  const float* b = which == 0 ? bq : which == 1 ? bk : bv;
  __bf16* y = which == 0 ? yq : which == 1 ? yk : yv;
  float sc = which == 0 ? qscale : 1.0f;
  proj_body4<float, __bf16>(x, W, b, y, sc, blockIdx.x * 4, Wl);
}

__global__ __launch_bounds__(256) void o_proj_kernel(
    const __bf16* __restrict__ x, const float* __restrict__ W,
    const float* __restrict__ b, float* __restrict__ y) {
  __shared__ alignas(16) __bf16 Wl[128][128];
  proj_body4<__bf16, float>(x, W, b, y, 1.0f, blockIdx.x * 4, Wl);
}

// ---------------------------------------------------------------------------
// epilogue-only swizzle (one-time O transpose staging)
__device__ __forceinline__ unsigned swz(int row, unsigned byteoff) {
  return byteoff ^ (((unsigned)(row ^ (row >> 3)) & 7u) << 4);
}

__device__ __forceinline__ unsigned pack2(float lo, float hi) {
  union { __bf16 h[2]; unsigned u; } r;
  r.h[0] = (__bf16)lo; r.h[1] = (__bf16)hi;
  return r.u;
}

// ---------------------------------------------------------------------------
// attn_kernel v11 = v9 loop structure + fragment-chunked LDS layouts.
//
// K layout: [cc 16][row 64][16B], byte = (cc*1024 + row*16) ^ ((cc&7)<<4).
//   chunk cc holds K cols cc*8..cc*8+7. QK read fragment (row, cols
//   kc*16+h*8..+7) = chunk kc*2+h -> addr = R[kc&3] + imm(kc,kvh) where
//   R[x] = h*1024 + (ql*16 ^ (h<<4) ^ (x<<5)).   [4 lane regs, 0 VALU/access]
// V layout: [c 8][d 128][16B], byte = (c*2048 + d*16 + (kv&7)*2) ^
//   ((d>>3)&7)<<4; chunk c holds kv c*8..c*8+7. PV read fragment (d-row,
//   kv ks*16+h*8..+7) = chunk ks*2+h -> addr = V[db&1] + imm(ks,db) where
//   V0 = 32768 + h*2048 + (ql*16 ^ ((ql>>3)<<4)), V1 = V0 ^ 64.
// Writes: K 2 lane regs (+512/+nb imms); V 8 lane regs vw_[e] (+8192/+nb).
// All accesses conflict-free (reads contiguous-permuted; K writes spread by
// (pr^cc)&7; V writes by e^(tid&7), 2 lanes/bank).
// Loop/softmax/P^T identical to v9 (single barrier/tile, prefetch after
// barrier, exp2-domain, T13 defer-rescale, permlane32_swap builtin).
// ---------------------------------------------------------------------------
__global__ __launch_bounds__(256, 2) void attn_kernel(
    const __bf16* __restrict__ q, const __bf16* __restrict__ k,
    const __bf16* __restrict__ v, __bf16* __restrict__ o) {
  __shared__ alignas(16) unsigned char smem[65536];

  const int tid = threadIdx.x;
  const int wave = tid >> 6, lane = tid & 63;
  const int ql = lane & 31;
  const int h = lane >> 5;

  const int bh = blockIdx.x;
  const int qbase = blockIdx.y * 128;
  const __bf16* qp = q + (size_t)bh * S_LEN * D_DIM;
  const __bf16* kp = k + (size_t)bh * S_LEN * D_DIM;
  const __bf16* vp = v + (size_t)bh * S_LEN * D_DIM;
  __bf16* op = o + (size_t)bh * S_LEN * D_DIM;

  const int qrow = qbase + wave * 32 + ql;
  bf16x8 qf[8];
#pragma unroll
  for (int kc = 0; kc < 8; ++kc)
    qf[kc] = *reinterpret_cast<const bf16x8*>(
        qp + (size_t)qrow * D_DIM + kc * 16 + h * 8);

  floatx16 ot[4];
#pragma unroll
  for (int d = 0; d < 4; ++d)
#pragma unroll
    for (int r = 0; r < 16; ++r) ot[d][r] = 0.f;
  float m_r = -1e30f, l_r = 0.f;

  // staging map
  const int cc = tid & 15;          // col/d chunk this thread stages
  const int pr = (tid >> 4) * 2;    // kv row-pair base
  const int ce = cc * 8;            // element base in d / K-col

  // ---- lane-resident address bases (loop-invariant, ~16 regs total) ----
  unsigned Rk[4];  // K reads, x = kc&3
#pragma unroll
  for (int x = 0; x < 4; ++x)
    Rk[x] = (unsigned)(h * 1024) +
            (((unsigned)(ql * 16)) ^ ((unsigned)h << 4) ^ ((unsigned)x << 5));
  const unsigned Rv0 = 32768u + (unsigned)(h * 2048) +
                       (((unsigned)(ql * 16)) ^ (((unsigned)(ql >> 3)) << 4));
  const unsigned Rv1 = Rv0 ^ 64u;
  const unsigned kx = ((unsigned)(cc & 7)) << 4;
  const unsigned Wk0 = ((unsigned)(cc * 1024 + pr * 16)) ^ kx;        // row pr
  const unsigned Wk1 = ((unsigned)(cc * 1024 + (pr + 1) * 16)) ^ kx;  // row pr+1
  unsigned Wv_[8];  // V writes: base(bits4-6=0) | ((e<<4)^X)
  {
    unsigned vbase = 32768u + (unsigned)((pr >> 3) * 2048 + ce * 16 + (pr & 7) * 2);
#pragma unroll
    for (int e = 0; e < 8; ++e)
      Wv_[e] = vbase | (((unsigned)e << 4) ^ kx);
  }

  // ---- prologue: stage tile 0 into buf 0 ----
  {
    const __bf16* kr = kp + (size_t)pr * D_DIM + ce;
    const __bf16* vr = vp + (size_t)pr * D_DIM + ce;
    bf16x8 kA0 = *reinterpret_cast<const bf16x8*>(kr);
    bf16x8 kA1 = *reinterpret_cast<const bf16x8*>(kr + D_DIM);
    bf16x8 kB0 = *reinterpret_cast<const bf16x8*>(kr + 32 * D_DIM);
    bf16x8 kB1 = *reinterpret_cast<const bf16x8*>(kr + 33 * D_DIM);
    union { bf16x8 v8; unsigned short s[8]; } vA0, vA1, vB0, vB1;
    vA0.v8 = *reinterpret_cast<const bf16x8*>(vr);
    vA1.v8 = *reinterpret_cast<const bf16x8*>(vr + D_DIM);
    vB0.v8 = *reinterpret_cast<const bf16x8*>(vr + 32 * D_DIM);
    vB1.v8 = *reinterpret_cast<const bf16x8*>(vr + 33 * D_DIM);
    *reinterpret_cast<bf16x8*>(smem + Wk0) = kA0;
    *reinterpret_cast<bf16x8*>(smem + Wk1) = kA1;
    *reinterpret_cast<bf16x8*>(smem + Wk0 + 512u) = kB0;
    *reinterpret_cast<bf16x8*>(smem + Wk1 + 512u) = kB1;
#pragma unroll
    for (int e = 0; e < 8; ++e) {
      unsigned w0 = (unsigned)vA0.s[e] | ((unsigned)vA1.s[e] << 16);
      unsigned w1 = (unsigned)vB0.s[e] | ((unsigned)vB1.s[e] << 16);
      *reinterpret_cast<unsigned*>(smem + Wv_[e]) = w0;
      *reinterpret_cast<unsigned*>(smem + Wv_[e] + 8192u) = w1;
    }
  }

  // running prefetch pointers (tile t+1)
  const __bf16* krp = kp + ((size_t)KVB + pr) * D_DIM + ce;
  const __bf16* vrp = vp + ((size_t)KVB + pr) * D_DIM + ce;

#pragma unroll 2
  for (int t = 0; t < NKV; ++t) {
    const unsigned cb = (unsigned)(t & 1) * 16384u;  // const after unroll-2
    const bool hn = (t + 1 < NKV);

    __syncthreads();  // buf[cur] staged; previous tile's readers done.

    bf16x8 kA0, kA1, kB0, kB1;
    union { bf16x8 v8; unsigned short s[8]; } vA0, vA1, vB0, vB1;
    if (hn) {  // issue next-tile global loads; consumed at loop tail
      kA0 = *reinterpret_cast<const bf16x8*>(krp);
      kA1 = *reinterpret_cast<const bf16x8*>(krp + D_DIM);
      kB0 = *reinterpret_cast<const bf16x8*>(krp + 32 * D_DIM);
      kB1 = *reinterpret_cast<const bf16x8*>(krp + 33 * D_DIM);
      vA0.v8 = *reinterpret_cast<const bf16x8*>(vrp);
      vA1.v8 = *reinterpret_cast<const bf16x8*>(vrp + D_DIM);
      vB0.v8 = *reinterpret_cast<const bf16x8*>(vrp + 32 * D_DIM);
      vB1.v8 = *reinterpret_cast<const bf16x8*>(vrp + 33 * D_DIM);
      krp += (size_t)KVB * D_DIM;
      vrp += (size_t)KVB * D_DIM;
    }

    // ---- QK^T: S^T[kv][q] ----
    floatx16 st[2];
#pragma unroll
    for (int kvh = 0; kvh < 2; ++kvh)
#pragma unroll
      for (int r = 0; r < 16; ++r) st[kvh][r] = 0.f;
    __builtin_amdgcn_s_setprio(1);
#pragma unroll
    for (int kc = 0; kc < 8; ++kc) {
      // addr = Rk[kc&3] + kc*2048 + kvh*512 + cb  (imm except lane base)
      bf16x8 kf0 = *reinterpret_cast<const bf16x8*>(
          smem + cb + Rk[kc & 3] + (unsigned)(kc * 2048));
      bf16x8 kf1 = *reinterpret_cast<const bf16x8*>(
          smem + cb + Rk[kc & 3] + (unsigned)(kc * 2048 + 512));
      st[0] = __builtin_amdgcn_mfma_f32_32x32x16_bf16(kf0, qf[kc], st[0], 0, 0, 0);
      st[1] = __builtin_amdgcn_mfma_f32_32x32x16_bf16(kf1, qf[kc], st[1], 0, 0, 0);
    }
    __builtin_amdgcn_s_setprio(0);

    // ---- softmax (exp2 domain), tree max/sum, T13 defer-rescale ----
    float t8[8];
#pragma unroll
    for (int i = 0; i < 8; ++i)
      t8[i] = fmaxf(fmaxf(st[0][i], st[0][i + 8]), fmaxf(st[1][i], st[1][i + 8]));
    float pmax = fmaxf(fmaxf(fmaxf(t8[0], t8[4]), fmaxf(t8[1], t8[5])),
                       fmaxf(fmaxf(t8[2], t8[6]), fmaxf(t8[3], t8[7])));
    pmax = fmaxf(pmax, __shfl_xor(pmax, 32));
    if (!__all(pmax - m_r <= 8.0f)) {
      float mnew = fmaxf(m_r, pmax);
      float sc_f = __builtin_amdgcn_exp2f(m_r - mnew);
      m_r = mnew;
      l_r *= sc_f;
#pragma unroll
      for (int d = 0; d < 4; ++d)
#pragma unroll
        for (int r = 0; r < 16; ++r) ot[d][r] *= sc_f;
    }
#pragma unroll
    for (int kvh = 0; kvh < 2; ++kvh)
#pragma unroll
      for (int r = 0; r < 16; ++r)
        st[kvh][r] = __builtin_amdgcn_exp2f(st[kvh][r] - m_r);
    float s8[8];
#pragma unroll
    for (int i = 0; i < 8; ++i)
      s8[i] = (st[0][i] + st[0][i + 8]) + (st[1][i] + st[1][i + 8]);
    float psum = ((s8[0] + s8[4]) + (s8[1] + s8[5])) +
                 ((s8[2] + s8[6]) + (s8[3] + s8[7]));
    psum += __shfl_xor(psum, 32);
    l_r += psum;

    // ---- P^T B-fragments + PV ----
#pragma unroll
    for (int ks = 0; ks < 4; ++ks) {
      const int kvh = ks >> 1;
      const int r2a = (2 * ks) & 3;
      const int r2b = r2a + 1;
      unsigned ua0 = pack2(st[kvh][r2a * 4 + 0], st[kvh][r2a * 4 + 1]);
      unsigned ua1 = pack2(st[kvh][r2a * 4 + 2], st[kvh][r2a * 4 + 3]);
      unsigned ub0 = pack2(st[kvh][r2b * 4 + 0], st[kvh][r2b * 4 + 1]);
      unsigned ub1 = pack2(st[kvh][r2b * 4 + 2], st[kvh][r2b * 4 + 3]);
      union { unsigned u[4]; bf16x8 v8; } pw;
#if __has_builtin(__builtin_amdgcn_permlane32_swap)
      {
        auto r0 = __builtin_amdgcn_permlane32_swap(ua0, ub0, false, false);
        auto r1 = __builtin_amdgcn_permlane32_swap(ua1, ub1, false, false);
        pw.u[0] = r0[0];
        pw.u[1] = r1[0];
        pw.u[2] = r0[1];
        pw.u[3] = r1[1];
      }
#else
      {
        unsigned a0x = __shfl_xor(ua0, 32), a1x = __shfl_xor(ua1, 32);
        unsigned b0x = __shfl_xor(ub0, 32), b1x = __shfl_xor(ub1, 32);
        pw.u[0] = h ? b0x : ua0;
        pw.u[1] = h ? b1x : ua1;
        pw.u[2] = h ? ub0 : a0x;
        pw.u[3] = h ? ub1 : a1x;
      }
#endif
      __builtin_amdgcn_s_setprio(1);
#pragma unroll
      for (int db = 0; db < 4; ++db) {
        // addr = Rv[db&1] + ks*4096 + db*512 + cb
        const unsigned base = (db & 1) ? Rv1 : Rv0;
        bf16x8 vf = *reinterpret_cast<const bf16x8*>(
            smem + cb + base + (unsigned)(ks * 4096 + db * 512));
        ot[db] = __builtin_amdgcn_mfma_f32_32x32x16_bf16(vf, pw.v8, ot[db], 0, 0, 0);
      }
      __builtin_amdgcn_s_setprio(0);
    }

    // ---- write staged tile t+1 into buf[nxt] (vmcnt wait lands here) ----
    if (hn) {
      const unsigned nb = cb ^ 16384u;
      *reinterpret_cast<bf16x8*>(smem + nb + Wk0) = kA0;
      *reinterpret_cast<bf16x8*>(smem + nb + Wk1) = kA1;
      *reinterpret_cast<bf16x8*>(smem + nb + Wk0 + 512u) = kB0;
      *reinterpret_cast<bf16x8*>(smem + nb + Wk1 + 512u) = kB1;
#pragma unroll
      for (int e = 0; e < 8; ++e) {
        unsigned w0 = (unsigned)vA0.s[e] | ((unsigned)vA1.s[e] << 16);
        unsigned w1 = (unsigned)vB0.s[e] | ((unsigned)vB1.s[e] << 16);
        *reinterpret_cast<unsigned*>(smem + nb + Wv_[e]) = w0;
        *reinterpret_cast<unsigned*>(smem + nb + Wv_[e] + 8192u) = w1;
      }
    }
  }

  // ---- epilogue: O^T -> LDS transpose -> coalesced stores ----
  __syncthreads();
  const float inv_l = 1.0f / l_r;
  const int qloc = wave * 32 + ql;
#pragma unroll
  for (int db = 0; db < 4; ++db)
#pragma unroll
    for (int r = 0; r < 16; ++r) {
      int d = db * 32 + (r & 3) + 8 * (r >> 2) + 4 * h;
      *reinterpret_cast<__bf16*>(smem + swz(qloc, qloc * 256u + d * 2u)) =
          (__bf16)(ot[db][r] * inv_l);
    }
  __syncthreads();
#pragma unroll
  for (int it = 0; it < 8; ++it) {
    int r = tid >> 1;
    int c = (tid & 1) * 64 + it * 8;
    bf16x8 val = *reinterpret_cast<const bf16x8*>(smem + swz(r, r * 256u + c * 2u));
    *reinterpret_cast<bf16x8*>(op + (size_t)(qbase + r) * D_DIM + c) = val;
  }
}

// ---------------------------------------------------------------------------
extern "C" void kernel_launch(void* const* d_in, const int* in_sizes, int n_in,
                              void* d_out, int out_size, void* d_ws, size_t ws_size,
                              hipStream_t stream) {
  const float* query = (const float*)d_in[0];
  const float* key_  = (const float*)d_in[1];
  const float* value = (const float*)d_in[2];
  const float* Wq = (const float*)d_in[3];
  const float* bq = (const float*)d_in[4];
  const float* Wk = (const float*)d_in[5];
  const float* bk = (const float*)d_in[6];
  const float* Wv = (const float*)d_in[7];
  const float* bv = (const float*)d_in[8];
  const float* Wo = (const float*)d_in[9];
  const float* bo = (const float*)d_in[10];

  __bf16* vws = (__bf16*)d_ws;
  __bf16* aws = vws + (size_t)NTOK * D_DIM;
  __bf16* qws = (__bf16*)d_out;
  __bf16* kws = qws + (size_t)NTOK * D_DIM;

  // q scale = log2(e)/sqrt(128): softmax runs in exp2 domain
  const float qscale = 0.1275174490036f;

  qkv_proj_kernel<<<dim3(NTOK / 256, 3), dim3(256), 0, stream>>>(
      query, key_, value, Wq, Wk, Wv, bq, bk, bv, qws, kws, vws, qscale);

  attn_kernel<<<dim3(32, 16), dim3(256), 0, stream>>>(qws, kws, vws, aws);

  o_proj_kernel<<<NTOK / 256, dim3(256), 0, stream>>>(aws, Wo, bo, (float*)d_out);
}